// Round 14
// baseline (193.989 us; speedup 1.0000x reference)
//
#include <hip/hip_runtime.h>
#include <math.h>

#define NUM_GRAPHS 512
#define D 128
#define NEG 0.01f
#define BN 128  // nodes per block in MFMA MLP kernel
#define NS 4    // pool row-slices per (graph, tensor)

typedef __attribute__((ext_vector_type(8))) short  bf16x8;  // MFMA A/B frag
typedef __attribute__((ext_vector_type(4))) float  f32x4;   // MFMA C/D frag
typedef __attribute__((ext_vector_type(4))) int    i32x4;

__device__ __forceinline__ unsigned short f2bf(float f) {
    unsigned u = __float_as_uint(f);
    u += 0x7fffu + ((u >> 16) & 1u);   // RNE
    return (unsigned short)(u >> 16);
}

// f32x8 -> 16B of bf16 via packed cvt
__device__ __forceinline__ bf16x8 cvt8(float4 a, float4 b) {
    unsigned w0, w1, w2, w3;
    asm("v_cvt_pk_bf16_f32 %0, %1, %2" : "=v"(w0) : "v"(a.x), "v"(a.y));
    asm("v_cvt_pk_bf16_f32 %0, %1, %2" : "=v"(w1) : "v"(a.z), "v"(a.w));
    asm("v_cvt_pk_bf16_f32 %0, %1, %2" : "=v"(w2) : "v"(b.x), "v"(b.y));
    asm("v_cvt_pk_bf16_f32 %0, %1, %2" : "=v"(w3) : "v"(b.z), "v"(b.w));
    i32x4 v; v[0] = (int)w0; v[1] = (int)w1; v[2] = (int)w2; v[3] = (int)w3;
    return __builtin_bit_cast(bf16x8, v);
}

// swizzled ushort index in the 128-row two-tile LDS image
__device__ __forceinline__ int swz128(int row, int k) {
    return (row >> 6) * 16384 + (row & 63) * 256 + (k ^ ((row & 7) << 3));
}

// raw barrier that does NOT drain vmcnt (keeps global prefetch in flight);
// lgkmcnt(0) publishes LDS writes / retires LDS reads.
#define LDS_BARRIER()                                                        \
    do {                                                                     \
        asm volatile("s_waitcnt lgkmcnt(0)" ::: "memory");                   \
        __builtin_amdgcn_s_barrier();                                        \
        asm volatile("" ::: "memory");                                       \
    } while (0)

#define FMAX4(a, b)                                                          \
    do {                                                                     \
        (a).x = fmaxf((a).x, (b).x); (a).y = fmaxf((a).y, (b).y);            \
        (a).z = fmaxf((a).z, (b).z); (a).w = fmaxf((a).w, (b).w);            \
    } while (0)
#define FADD4(a, b)                                                          \
    do {                                                                     \
        (a).x += (b).x; (a).y += (b).y; (a).z += (b).z; (a).w += (b).w;      \
    } while (0)

// ---------------------------------------------------------------------------
// Kernel 0: segment bounds. seg[g] = lower_bound(batch, g), g in [0, 512].
// ---------------------------------------------------------------------------
__global__ __launch_bounds__(256) void bounds_kernel(
    const int* __restrict__ batch, int N, int* __restrict__ seg)
{
    const int g = blockIdx.x * 256 + threadIdx.x;
    if (g <= NUM_GRAPHS) {
        int lo = 0, hi = N;
        while (lo < hi) { int m = (lo + hi) >> 1; if (batch[m] < g) lo = m + 1; else hi = m; }
        seg[g] = lo;
    }
}

// ---------------------------------------------------------------------------
// Kernel 1: sliced per-graph segment max+sum partials (pure reduction).
// grid=(512, 2, NS); 4 independent acc streams for MLP.
// ---------------------------------------------------------------------------
__global__ __launch_bounds__(256) void pool_kernel(
    const float* __restrict__ h_topo, const float* __restrict__ h_geom,
    const int* __restrict__ seg, int N, float* __restrict__ pp)
{
    const int g = blockIdx.x, t = blockIdx.y, s = blockIdx.z;
    const float* __restrict__ h = t ? h_geom : h_topo;

    const int start = seg[g], end = seg[g + 1];
    const int len = end - start;
    const int r0  = start + (int)(((long long)len * s) / NS);
    const int r1  = start + (int)(((long long)len * (s + 1)) / NS);

    const int c = threadIdx.x & 31;   // float4 column
    const int r = threadIdx.x >> 5;   // 0..7 row phase

    float4 mxA = make_float4(-INFINITY, -INFINITY, -INFINITY, -INFINITY);
    float4 mxB = mxA, mxC = mxA, mxD = mxA;
    float4 smA = make_float4(0.f, 0.f, 0.f, 0.f);
    float4 smB = smA, smC = smA, smD = smA;

    int row = r0 + r;
    for (; row + 24 < r1; row += 32) {
        float4 v0 = *(const float4*)(h + (size_t)row * D + c * 4);
        float4 v1 = *(const float4*)(h + (size_t)(row + 8)  * D + c * 4);
        float4 v2 = *(const float4*)(h + (size_t)(row + 16) * D + c * 4);
        float4 v3 = *(const float4*)(h + (size_t)(row + 24) * D + c * 4);
        FMAX4(mxA, v0); FADD4(smA, v0);
        FMAX4(mxB, v1); FADD4(smB, v1);
        FMAX4(mxC, v2); FADD4(smC, v2);
        FMAX4(mxD, v3); FADD4(smD, v3);
    }
    for (; row < r1; row += 8) {
        float4 v = *(const float4*)(h + (size_t)row * D + c * 4);
        FMAX4(mxA, v); FADD4(smA, v);
    }
    FMAX4(mxA, mxB); FMAX4(mxC, mxD); FMAX4(mxA, mxC);
    FADD4(smA, smB); FADD4(smC, smD); FADD4(smA, smC);

    __shared__ float4 smx[256], ssm[256];
    smx[threadIdx.x] = mxA; ssm[threadIdx.x] = smA;
    __syncthreads();
    #pragma unroll
    for (int st = 4; st > 0; st >>= 1) {
        if (r < st) {
            float4 a = smx[threadIdx.x + st * 32];
            float4 b = ssm[threadIdx.x + st * 32];
            float4 m0 = smx[threadIdx.x];
            float4 s0 = ssm[threadIdx.x];
            FMAX4(m0, a); FADD4(s0, b);
            smx[threadIdx.x] = m0; ssm[threadIdx.x] = s0;
        }
        __syncthreads();
    }
    if (r == 0) {
        float* dst = pp + ((size_t)(g * 2 + t) * NS + s) * 256;
        *(float4*)(dst + c * 4)       = smx[threadIdx.x];   // raw max partial
        *(float4*)(dst + 128 + c * 4) = ssm[threadIdx.x];   // raw sum partial
    }
}

// ---------------------------------------------------------------------------
// Kernel 2: finalize partials + per-graph bias
// P[g][j] = b1[j] + pooled[g] . W1[pooled rows][j]
// ---------------------------------------------------------------------------
__global__ __launch_bounds__(256) void pmat_kernel(
    const float* __restrict__ pp, const int* __restrict__ seg,
    const float* __restrict__ W1, const float* __restrict__ b1,
    float* __restrict__ P)
{
    const int g = blockIdx.x;
    const int j = threadIdx.x;

    const int start = seg[g], end = seg[g + 1];
    const float inv   = 1.0f / fmaxf((float)(end - start), 1.0f);
    const bool  empty = (end <= start);

    __shared__ float pl[512];
    #pragma unroll
    for (int e0 = 0; e0 < 2; ++e0) {
        const int e = j + e0 * 256;
        const int t = e >> 8, i = e & 255;
        const float* q = pp + (size_t)(g * 2 + t) * NS * 256 + i;
        float v;
        if (i < 128)
            v = fmaxf(fmaxf(q[0], q[256]), fmaxf(q[512], q[768]));
        else
            v = (q[0] + q[256] + q[512] + q[768]) * inv;
        pl[e] = empty ? 0.f : v;
    }
    __syncthreads();

    float acc = b1[j];
    #pragma unroll 8
    for (int k = 0; k < 256; ++k)          // t_max,t_mean -> W1 rows 128..383
        acc += pl[k] * W1[(size_t)(128 + k) * 256 + j];
    #pragma unroll 8
    for (int k = 0; k < 256; ++k)          // g_max,g_mean -> W1 rows 512..767
        acc += pl[256 + k] * W1[(size_t)(512 + k) * 256 + j];

    P[(size_t)g * 256 + j] = acc;
}

// ---------------------------------------------------------------------------
// Kernel 3: weight pre-convert to transposed bf16.
// W1bT[n][k]: n = H-col, k = X-feature (kmap: topo 0..127 -> rows 0..127,
// geom 128..255 -> rows 384..511). W2bT[j][c]: j = out-col, c = H-col.
// ---------------------------------------------------------------------------
__global__ __launch_bounds__(256) void wconv_kernel(
    const float* __restrict__ W1, const float* __restrict__ W2,
    unsigned short* __restrict__ W1bT, unsigned short* __restrict__ W2bT)
{
    const int idx = blockIdx.x * 256 + threadIdx.x;
    if (idx < 256 * 256) {
        const int n = idx >> 8, k = idx & 255;
        const int kk = (k < 128) ? k : (k + 256);
        W1bT[idx] = f2bf(W1[(size_t)kk * 256 + n]);
    } else {
        const int j = idx - 256 * 256;
        if (j < 128 * 256) {
            const int n = j >> 8, k = j & 255;
            W2bT[j] = f2bf(W2[(size_t)k * 128 + n]);
        }
    }
}

// ---------------------------------------------------------------------------
// Kernel 4: fused MFMA MLP, LDS-pipe-minimized. 128 nodes/block, 8 waves.
// GEMM1 TRANSPOSED: D[j][node] = W1'^T Xt; wave grid 2 (node-halves, wr) x
// 4 (H-col quarters, wc); wave tile 64 nodes x 64 H-cols -> each wave reads
// only HALF the X tile (32 ds_read_b128 vs 64). D gives 4 consecutive j per
// lane -> P folds as per-lane float4, epilogue packs 4 bf16 per ds_write_b64
// (16 b64 writes/thread vs 64 scalar u16).
// GEMM2 transposed as in R13 (full-128B-line NT stores per wave).
// ---------------------------------------------------------------------------
__global__ __launch_bounds__(512, 4) void mlp_mfma(
    const float* __restrict__ h_topo, const float* __restrict__ h_geom,
    const int* __restrict__ batch, const float* __restrict__ P,
    const unsigned short* __restrict__ W1bT, const unsigned short* __restrict__ W2bT,
    const float* __restrict__ b2, float* __restrict__ out, int N)
{
    __shared__ unsigned short xs[128 * 256];   // 64 KB, X then H (swz128 layout)
    __shared__ int gid[128];

    const int tid  = threadIdx.x;
    const int wave = tid >> 6, lane = tid & 63;
    const int base = (gridDim.x - 1 - blockIdx.x) * BN;   // reverse order

    // ---- stage X: row = tid>>2 (0..127), kq = tid&3 (64-dim chunk) ----
    {
        const int row  = tid >> 2, kq = tid & 3;
        const int node = min(base + row, N - 1);
        const float* src = (kq < 2) ? h_topo + (size_t)node * D + kq * 64
                                    : h_geom + (size_t)node * D + (kq - 2) * 64;
        #pragma unroll
        for (int i = 0; i < 8; ++i) {
            float4 a = ((const float4*)src)[2 * i];
            float4 b = ((const float4*)src)[2 * i + 1];
            *(bf16x8*)&xs[swz128(row, kq * 64 + i * 8)] = cvt8(a, b);
        }
    }
    if (tid < 128) gid[tid] = batch[min(base + tid, N - 1)];

    const int g0 = batch[base];
    const int g1 = batch[min(base + 127, N - 1)];
    const bool uni = (g0 == g1);

    const int lhi = lane >> 4;   // 0..3
    const int llo = lane & 15;   // 0..15

    // GEMM1 wave tile: nodes [wr*64, wr*64+64), H-cols [wc*64, wc*64+64)
    const int wr = wave >> 2, wc = wave & 3;

    // W1 A-frag base: row = H-col (wc*64 + ct*16 + llo), k offset lhi*8
    const unsigned short* w1p = W1bT + (size_t)(wc * 64 + llo) * 256 + lhi * 8;

    float4 pf4[4];
    if (uni) {
        #pragma unroll
        for (int ct = 0; ct < 4; ++ct)
            pf4[ct] = *(const float4*)(P + (size_t)g0 * 256 + wc * 64 + ct * 16 + lhi * 4);
    }

    // ---- preload GEMM1 ks=0,1 W1 frags ----
    bf16x8 aW[2][4];
    #pragma unroll
    for (int ct = 0; ct < 4; ++ct) {
        aW[0][ct] = *(const bf16x8*)(w1p + (size_t)ct * 16 * 256);
        aW[1][ct] = *(const bf16x8*)(w1p + (size_t)ct * 16 * 256 + 32);
    }

    LDS_BARRIER();   // X image + gid published (lgkm only; vm loads in flight)

    // ---- GEMM1T: D[j][node]; acc[rt][ct], rt = node tile, ct = j tile ----
    f32x4 acc[4][4];
    #pragma unroll
    for (int rt = 0; rt < 4; ++rt)
        #pragma unroll
        for (int ct = 0; ct < 4; ++ct)
            acc[rt][ct] = uni ? (f32x4){pf4[ct].x, pf4[ct].y, pf4[ct].z, pf4[ct].w}
                              : (f32x4){0.f, 0.f, 0.f, 0.f};

    #pragma unroll
    for (int ks = 0; ks < 8; ++ks) {
        const int kb = ks * 32 + lhi * 8;
        bf16x8 bX[4];
        #pragma unroll
        for (int rt = 0; rt < 4; ++rt)
            bX[rt] = *(const bf16x8*)&xs[swz128(wr * 64 + rt * 16 + llo, kb)];
        __builtin_amdgcn_s_setprio(1);
        #pragma unroll
        for (int rt = 0; rt < 4; ++rt)
            #pragma unroll
            for (int ct = 0; ct < 4; ++ct)
                acc[rt][ct] = __builtin_amdgcn_mfma_f32_16x16x32_bf16(
                    aW[ks & 1][ct], bX[rt], acc[rt][ct], 0, 0, 0);
        __builtin_amdgcn_s_setprio(0);
        if (ks < 6) {
            const int kbn = (ks + 2) * 32;
            #pragma unroll
            for (int ct = 0; ct < 4; ++ct)
                aW[ks & 1][ct] = *(const bf16x8*)(w1p + (size_t)ct * 16 * 256 + kbn);
        }
    }

    // ---- GEMM2 tiling: wr2 node-half, wc2 j-quarter (one 128B line) ----
    const int wr2 = wave >> 2, wc2 = wave & 3;
    const unsigned short* w2pA = W2bT + (size_t)(wc2 * 32 + llo) * 256 + lhi * 8;
    const unsigned short* w2pB = W2bT + (size_t)(wc2 * 32 + 16 + llo) * 256 + lhi * 8;

    // issue GEMM2 ks=0,1 W2 frags (in flight across barriers)
    bf16x8 aW2[2][2];
    aW2[0][0] = *(const bf16x8*)(w2pA);
    aW2[0][1] = *(const bf16x8*)(w2pB);
    aW2[1][0] = *(const bf16x8*)(w2pA + 32);
    aW2[1][1] = *(const bf16x8*)(w2pB + 32);

    LDS_BARRIER();   // all waves done reading X (lgkm only)

    // ---- epilogue: (+P gather if boundary), LeakyReLU, packed b64 H-writes ----
    #pragma unroll
    for (int rt = 0; rt < 4; ++rt) {
        const int nrow = wr * 64 + rt * 16 + llo;
        int gg = 0;
        if (!uni) gg = gid[nrow];
        #pragma unroll
        for (int ct = 0; ct < 4; ++ct) {
            const int j0 = wc * 64 + ct * 16 + lhi * 4;
            float4 v = make_float4(acc[rt][ct][0], acc[rt][ct][1],
                                   acc[rt][ct][2], acc[rt][ct][3]);
            if (!uni) {
                float4 pv = *(const float4*)(P + (size_t)gg * 256 + j0);
                v.x += pv.x; v.y += pv.y; v.z += pv.z; v.w += pv.w;
            }
            v.x = fmaxf(v.x, NEG * v.x); v.y = fmaxf(v.y, NEG * v.y);
            v.z = fmaxf(v.z, NEG * v.z); v.w = fmaxf(v.w, NEG * v.w);
            unsigned w0, w1;
            asm("v_cvt_pk_bf16_f32 %0, %1, %2" : "=v"(w0) : "v"(v.x), "v"(v.y));
            asm("v_cvt_pk_bf16_f32 %0, %1, %2" : "=v"(w1) : "v"(v.z), "v"(v.w));
            uint2 hw; hw.x = w0; hw.y = w1;
            *(uint2*)&xs[swz128(nrow, j0)] = hw;   // ds_write_b64
        }
    }

    LDS_BARRIER();   // H published

    // ---- GEMM2T: D[j][node], wave = 64 nodes x 32 j-cols ----
    f32x4 acc2[4][2];
    {
        const float4 bbA = *(const float4*)(b2 + wc2 * 32 + lhi * 4);
        const float4 bbB = *(const float4*)(b2 + wc2 * 32 + 16 + lhi * 4);
        #pragma unroll
        for (int nt = 0; nt < 4; ++nt) {
            acc2[nt][0] = (f32x4){bbA.x, bbA.y, bbA.z, bbA.w};
            acc2[nt][1] = (f32x4){bbB.x, bbB.y, bbB.z, bbB.w};
        }
    }
    #pragma unroll
    for (int ks = 0; ks < 8; ++ks) {
        const int kb = ks * 32 + lhi * 8;
        bf16x8 bH[4];
        #pragma unroll
        for (int nt = 0; nt < 4; ++nt)
            bH[nt] = *(const bf16x8*)&xs[swz128(wr2 * 64 + nt * 16 + llo, kb)];
        __builtin_amdgcn_s_setprio(1);
        #pragma unroll
        for (int nt = 0; nt < 4; ++nt) {
            acc2[nt][0] = __builtin_amdgcn_mfma_f32_16x16x32_bf16(
                aW2[ks & 1][0], bH[nt], acc2[nt][0], 0, 0, 0);
            acc2[nt][1] = __builtin_amdgcn_mfma_f32_16x16x32_bf16(
                aW2[ks & 1][1], bH[nt], acc2[nt][1], 0, 0, 0);
        }
        __builtin_amdgcn_s_setprio(0);
        if (ks < 6) {
            aW2[ks & 1][0] = *(const bf16x8*)(w2pA + (ks + 2) * 32);
            aW2[ks & 1][1] = *(const bf16x8*)(w2pB + (ks + 2) * 32);
        }
    }

    // ---- store out: full 128B lines per wave, non-temporal float4 ----
    #pragma unroll
    for (int nt = 0; nt < 4; ++nt) {
        const int node = base + wr2 * 64 + nt * 16 + llo;
        if (node < N) {
            float* op = out + (size_t)node * 128 + wc2 * 32 + lhi * 4;
            __builtin_nontemporal_store(acc2[nt][0], (f32x4*)op);
            __builtin_nontemporal_store(acc2[nt][1], (f32x4*)(op + 16));
        }
    }
}

// ---------------------------------------------------------------------------
extern "C" void kernel_launch(void* const* d_in, const int* in_sizes, int n_in,
                              void* d_out, int out_size, void* d_ws, size_t ws_size,
                              hipStream_t stream)
{
    const float* h_topo = (const float*)d_in[0];
    const float* h_geom = (const float*)d_in[1];
    const int*   batch  = (const int*)  d_in[2];
    const float* W1     = (const float*)d_in[3];
    const float* b1     = (const float*)d_in[4];
    const float* W2     = (const float*)d_in[5];
    const float* b2     = (const float*)d_in[6];
    float* out = (float*)d_out;

    const int N = in_sizes[0] / D;   // 200000

    // ws layout: pp (4MB) | P (512KB) | W1bT | W2bT | seg (~2KB)
    float*          pp   = (float*)d_ws;
    float*          P    = pp + (size_t)NUM_GRAPHS * 2 * NS * 256;
    unsigned short* W1bT = (unsigned short*)(P + (size_t)NUM_GRAPHS * 256);
    unsigned short* W2bT = W1bT + 256 * 256;
    int*            seg  = (int*)(W2bT + 128 * 256);

    bounds_kernel<<<3, 256, 0, stream>>>(batch, N, seg);
    wconv_kernel<<<(256 * 256 + 128 * 256) / 256, 256, 0, stream>>>(W1, W2, W1bT, W2bT);
    pool_kernel<<<dim3(NUM_GRAPHS, 2, NS), 256, 0, stream>>>(h_topo, h_geom, seg, N, pp);
    pmat_kernel<<<NUM_GRAPHS, 256, 0, stream>>>(pp, seg, W1, b1, P);

    const int nblocks = (N + BN - 1) / BN;   // 1563
    mlp_mfma<<<nblocks, 512, 0, stream>>>(h_topo, h_geom, batch, P,
                                          W1bT, W2bT, b2, out, N);
}

// Round 15
// 187.007 us; speedup vs baseline: 1.0373x; 1.0373x over previous
//
#include <hip/hip_runtime.h>
#include <math.h>

#define NUM_GRAPHS 512
#define D 128
#define NEG 0.01f
#define BN 64   // nodes per block in MFMA MLP kernel (32KB LDS -> 4 blocks/CU)
#define NS 8    // pool row-slices per (graph, tensor)

typedef __attribute__((ext_vector_type(8))) short  bf16x8;  // MFMA A/B frag
typedef __attribute__((ext_vector_type(4))) float  f32x4;   // MFMA C/D frag
typedef __attribute__((ext_vector_type(4))) int    i32x4;

__device__ __forceinline__ unsigned short f2bf(float f) {
    unsigned u = __float_as_uint(f);
    u += 0x7fffu + ((u >> 16) & 1u);   // RNE
    return (unsigned short)(u >> 16);
}

// f32x8 -> 16B of bf16 via packed cvt
__device__ __forceinline__ bf16x8 cvt8(float4 a, float4 b) {
    unsigned w0, w1, w2, w3;
    asm("v_cvt_pk_bf16_f32 %0, %1, %2" : "=v"(w0) : "v"(a.x), "v"(a.y));
    asm("v_cvt_pk_bf16_f32 %0, %1, %2" : "=v"(w1) : "v"(a.z), "v"(a.w));
    asm("v_cvt_pk_bf16_f32 %0, %1, %2" : "=v"(w2) : "v"(b.x), "v"(b.y));
    asm("v_cvt_pk_bf16_f32 %0, %1, %2" : "=v"(w3) : "v"(b.z), "v"(b.w));
    i32x4 v; v[0] = (int)w0; v[1] = (int)w1; v[2] = (int)w2; v[3] = (int)w3;
    return __builtin_bit_cast(bf16x8, v);
}

// swizzled ushort index in the 64-row LDS tile
__device__ __forceinline__ int swz64(int row, int k) {
    return row * 256 + (k ^ ((row & 7) << 3));
}

// raw barrier that does NOT drain vmcnt (keeps global prefetch in flight);
// lgkmcnt(0) publishes LDS writes / retires LDS reads.
#define LDS_BARRIER()                                                        \
    do {                                                                     \
        asm volatile("s_waitcnt lgkmcnt(0)" ::: "memory");                   \
        __builtin_amdgcn_s_barrier();                                        \
        asm volatile("" ::: "memory");                                       \
    } while (0)

#define FMAX4(a, b)                                                          \
    do {                                                                     \
        (a).x = fmaxf((a).x, (b).x); (a).y = fmaxf((a).y, (b).y);            \
        (a).z = fmaxf((a).z, (b).z); (a).w = fmaxf((a).w, (b).w);            \
    } while (0)
#define FADD4(a, b)                                                          \
    do {                                                                     \
        (a).x += (b).x; (a).y += (b).y; (a).z += (b).z; (a).w += (b).w;      \
    } while (0)

// ---------------------------------------------------------------------------
// Kernel 0: segment bounds. seg[g] = lower_bound(batch, g), g in [0, 512].
// ---------------------------------------------------------------------------
__global__ __launch_bounds__(256) void bounds_kernel(
    const int* __restrict__ batch, int N, int* __restrict__ seg)
{
    const int g = blockIdx.x * 256 + threadIdx.x;
    if (g <= NUM_GRAPHS) {
        int lo = 0, hi = N;
        while (lo < hi) { int m = (lo + hi) >> 1; if (batch[m] < g) lo = m + 1; else hi = m; }
        seg[g] = lo;
    }
}

// ---------------------------------------------------------------------------
// Kernel 1: sliced per-graph segment max+sum partials (pure reduction).
// grid=(512, 2, NS); 4 independent acc streams for MLP.
// pp[((g*2+t)*NS+s)*256 + {0..127: max, 128..255: sum}]
// ---------------------------------------------------------------------------
__global__ __launch_bounds__(256) void pool_kernel(
    const float* __restrict__ h_topo, const float* __restrict__ h_geom,
    const int* __restrict__ seg, int N, float* __restrict__ pp)
{
    const int g = blockIdx.x, t = blockIdx.y, s = blockIdx.z;
    const float* __restrict__ h = t ? h_geom : h_topo;

    const int start = seg[g], end = seg[g + 1];
    const int len = end - start;
    const int r0  = start + (int)(((long long)len * s) / NS);
    const int r1  = start + (int)(((long long)len * (s + 1)) / NS);

    const int c = threadIdx.x & 31;   // float4 column
    const int r = threadIdx.x >> 5;   // 0..7 row phase

    float4 mxA = make_float4(-INFINITY, -INFINITY, -INFINITY, -INFINITY);
    float4 mxB = mxA, mxC = mxA, mxD = mxA;
    float4 smA = make_float4(0.f, 0.f, 0.f, 0.f);
    float4 smB = smA, smC = smA, smD = smA;

    int row = r0 + r;
    for (; row + 24 < r1; row += 32) {
        float4 v0 = *(const float4*)(h + (size_t)row * D + c * 4);
        float4 v1 = *(const float4*)(h + (size_t)(row + 8)  * D + c * 4);
        float4 v2 = *(const float4*)(h + (size_t)(row + 16) * D + c * 4);
        float4 v3 = *(const float4*)(h + (size_t)(row + 24) * D + c * 4);
        FMAX4(mxA, v0); FADD4(smA, v0);
        FMAX4(mxB, v1); FADD4(smB, v1);
        FMAX4(mxC, v2); FADD4(smC, v2);
        FMAX4(mxD, v3); FADD4(smD, v3);
    }
    for (; row < r1; row += 8) {
        float4 v = *(const float4*)(h + (size_t)row * D + c * 4);
        FMAX4(mxA, v); FADD4(smA, v);
    }
    FMAX4(mxA, mxB); FMAX4(mxC, mxD); FMAX4(mxA, mxC);
    FADD4(smA, smB); FADD4(smC, smD); FADD4(smA, smC);

    __shared__ float4 smx[256], ssm[256];
    smx[threadIdx.x] = mxA; ssm[threadIdx.x] = smA;
    __syncthreads();
    #pragma unroll
    for (int st = 4; st > 0; st >>= 1) {
        if (r < st) {
            float4 a = smx[threadIdx.x + st * 32];
            float4 b = ssm[threadIdx.x + st * 32];
            float4 m0 = smx[threadIdx.x];
            float4 s0 = ssm[threadIdx.x];
            FMAX4(m0, a); FADD4(s0, b);
            smx[threadIdx.x] = m0; ssm[threadIdx.x] = s0;
        }
        __syncthreads();
    }
    if (r == 0) {
        float* dst = pp + ((size_t)(g * 2 + t) * NS + s) * 256;
        *(float4*)(dst + c * 4)       = smx[threadIdx.x];   // raw max partial
        *(float4*)(dst + 128 + c * 4) = ssm[threadIdx.x];   // raw sum partial
    }
}

// ---------------------------------------------------------------------------
// Kernel 2: finalize partials + per-graph bias
// P[g][j] = b1[j] + pooled[g] . W1[pooled rows][j]
// ---------------------------------------------------------------------------
__global__ __launch_bounds__(256) void pmat_kernel(
    const float* __restrict__ pp, const int* __restrict__ seg,
    const float* __restrict__ W1, const float* __restrict__ b1,
    float* __restrict__ P)
{
    const int g = blockIdx.x;
    const int j = threadIdx.x;

    const int start = seg[g], end = seg[g + 1];
    const float inv   = 1.0f / fmaxf((float)(end - start), 1.0f);
    const bool  empty = (end <= start);

    __shared__ float pl[512];
    #pragma unroll
    for (int e0 = 0; e0 < 2; ++e0) {
        const int e = j + e0 * 256;
        const int t = e >> 8, i = e & 255;
        const float* q = pp + (size_t)(g * 2 + t) * NS * 256 + i;
        float v;
        if (i < 128) {
            v = q[0];
            #pragma unroll
            for (int s = 1; s < NS; ++s) v = fmaxf(v, q[s * 256]);
        } else {
            v = q[0];
            #pragma unroll
            for (int s = 1; s < NS; ++s) v += q[s * 256];
            v *= inv;
        }
        pl[e] = empty ? 0.f : v;
    }
    __syncthreads();

    float acc = b1[j];
    #pragma unroll 8
    for (int k = 0; k < 256; ++k)          // t_max,t_mean -> W1 rows 128..383
        acc += pl[k] * W1[(size_t)(128 + k) * 256 + j];
    #pragma unroll 8
    for (int k = 0; k < 256; ++k)          // g_max,g_mean -> W1 rows 512..767
        acc += pl[256 + k] * W1[(size_t)(512 + k) * 256 + j];

    P[(size_t)g * 256 + j] = acc;
}

// ---------------------------------------------------------------------------
// Kernel 3: weight pre-convert to transposed bf16.
// ---------------------------------------------------------------------------
__global__ __launch_bounds__(256) void wconv_kernel(
    const float* __restrict__ W1, const float* __restrict__ W2,
    unsigned short* __restrict__ W1bT, unsigned short* __restrict__ W2bT)
{
    const int idx = blockIdx.x * 256 + threadIdx.x;
    if (idx < 256 * 256) {
        const int n = idx >> 8, k = idx & 255;
        const int kk = (k < 128) ? k : (k + 256);
        W1bT[idx] = f2bf(W1[(size_t)kk * 256 + n]);
    } else {
        const int j = idx - 256 * 256;
        if (j < 128 * 256) {
            const int n = j >> 8, k = j & 255;
            W2bT[j] = f2bf(W2[(size_t)k * 128 + n]);
        }
    }
}

// ---------------------------------------------------------------------------
// Kernel 4: fused MFMA MLP. 64 nodes/block, 4 waves (256 thr), 32KB LDS ->
// 4 blocks/CU co-resident for finer HBM duty-cycle interleave.
// GEMM1 normal orientation (wave owns 64 H-cols); GEMM2 transposed with
// full-128B-line NT stores (wave owns all 64 nodes x 32 j-cols = whole lines).
// Reverse block order for L3 freshness.
// ---------------------------------------------------------------------------
__global__ __launch_bounds__(256, 4) void mlp_mfma(
    const float* __restrict__ h_topo, const float* __restrict__ h_geom,
    const int* __restrict__ batch, const float* __restrict__ P,
    const unsigned short* __restrict__ W1bT, const unsigned short* __restrict__ W2bT,
    const float* __restrict__ b2, float* __restrict__ out, int N)
{
    __shared__ unsigned short xs[64 * 256];   // 32 KB, X then H (swz64 layout)
    __shared__ int gid[64];

    const int tid  = threadIdx.x;
    const int wave = tid >> 6, lane = tid & 63;
    const int base = (gridDim.x - 1 - blockIdx.x) * BN;   // reverse order

    // ---- stage X: row = tid>>2 (0..63), kq = tid&3 (64-dim chunk) ----
    {
        const int row  = tid >> 2, kq = tid & 3;
        const int node = min(base + row, N - 1);
        const float* src = (kq < 2) ? h_topo + (size_t)node * D + kq * 64
                                    : h_geom + (size_t)node * D + (kq - 2) * 64;
        #pragma unroll
        for (int i = 0; i < 8; ++i) {
            float4 a = ((const float4*)src)[2 * i];
            float4 b = ((const float4*)src)[2 * i + 1];
            *(bf16x8*)&xs[swz64(row, kq * 64 + i * 8)] = cvt8(a, b);
        }
    }
    if (tid < 64) gid[tid] = batch[min(base + tid, N - 1)];

    const int g0 = batch[base];
    const int g1 = batch[min(base + 63, N - 1)];
    const bool uni = (g0 == g1);

    const int lhi = lane >> 4;   // 0..3
    const int llo = lane & 15;   // 0..15

    // GEMM1: wave owns H-cols [64w, 64w+64)
    const unsigned short* w1p = W1bT + (size_t)(wave * 64 + llo) * 256 + lhi * 8;

    float pf[4];
    if (uni) {
        #pragma unroll
        for (int ct = 0; ct < 4; ++ct)
            pf[ct] = P[(size_t)g0 * 256 + wave * 64 + ct * 16 + llo];
    }

    // ---- preload GEMM1 ks=0,1 weight frags (stay pending across barrier) ----
    bf16x8 bfr[2][4];
    #pragma unroll
    for (int ct = 0; ct < 4; ++ct) {
        bfr[0][ct] = *(const bf16x8*)(w1p + (size_t)ct * 16 * 256);
        bfr[1][ct] = *(const bf16x8*)(w1p + (size_t)ct * 16 * 256 + 32);
    }

    LDS_BARRIER();   // X image published (lgkm only; weight vm loads in flight)

    // ---- GEMM1: 4 row-tiles x 4 col-tiles, dist-2 W prefetch ----
    f32x4 acc[4][4];
    #pragma unroll
    for (int rt = 0; rt < 4; ++rt)
        #pragma unroll
        for (int ct = 0; ct < 4; ++ct) {
            const float p = uni ? pf[ct] : 0.f;
            acc[rt][ct] = (f32x4){p, p, p, p};
        }

    #pragma unroll
    for (int ks = 0; ks < 8; ++ks) {
        const int kb = ks * 32 + lhi * 8;
        bf16x8 afr[4];
        #pragma unroll
        for (int rt = 0; rt < 4; ++rt)
            afr[rt] = *(const bf16x8*)&xs[swz64(rt * 16 + llo, kb)];
        __builtin_amdgcn_s_setprio(1);
        #pragma unroll
        for (int rt = 0; rt < 4; ++rt)
            #pragma unroll
            for (int ct = 0; ct < 4; ++ct)
                acc[rt][ct] = __builtin_amdgcn_mfma_f32_16x16x32_bf16(
                    afr[rt], bfr[ks & 1][ct], acc[rt][ct], 0, 0, 0);
        __builtin_amdgcn_s_setprio(0);
        if (ks < 6) {
            const int kbn = (ks + 2) * 32;
            #pragma unroll
            for (int ct = 0; ct < 4; ++ct)
                bfr[ks & 1][ct] = *(const bf16x8*)(w1p + (size_t)ct * 16 * 256 + kbn);
        }
    }

    // ---- GEMM2 tiling: wave owns j-cols [32w, 32w+32) (one 128B line) ----
    const unsigned short* w2pA = W2bT + (size_t)(wave * 32 + llo) * 256 + lhi * 8;
    const unsigned short* w2pB = W2bT + (size_t)(wave * 32 + 16 + llo) * 256 + lhi * 8;

    // issue GEMM2 ks=0,1 W2 frags (in flight across barriers)
    bf16x8 aW2[2][2];
    aW2[0][0] = *(const bf16x8*)(w2pA);
    aW2[0][1] = *(const bf16x8*)(w2pB);
    aW2[1][0] = *(const bf16x8*)(w2pA + 32);
    aW2[1][1] = *(const bf16x8*)(w2pB + 32);

    LDS_BARRIER();   // all waves done reading X (lgkm only)

    // ---- epilogue 1: (+P if boundary tile), LeakyReLU, H -> xs (bf16) ----
    #pragma unroll
    for (int rt = 0; rt < 4; ++rt) {
        #pragma unroll
        for (int ct = 0; ct < 4; ++ct) {
            const int col = wave * 64 + ct * 16 + llo;
            #pragma unroll
            for (int q = 0; q < 4; ++q) {
                const int row = rt * 16 + lhi * 4 + q;
                float v = acc[rt][ct][q];
                if (!uni) v += P[(size_t)gid[row] * 256 + col];
                v = fmaxf(v, NEG * v);   // LeakyReLU
                xs[swz64(row, col)] = f2bf(v);
            }
        }
    }

    LDS_BARRIER();   // H published

    // ---- GEMM2T: D[j][node], wave = 64 nodes x 32 j-cols ----
    f32x4 acc2[4][2];
    {
        const float4 bbA = *(const float4*)(b2 + wave * 32 + lhi * 4);
        const float4 bbB = *(const float4*)(b2 + wave * 32 + 16 + lhi * 4);
        #pragma unroll
        for (int nt = 0; nt < 4; ++nt) {
            acc2[nt][0] = (f32x4){bbA.x, bbA.y, bbA.z, bbA.w};
            acc2[nt][1] = (f32x4){bbB.x, bbB.y, bbB.z, bbB.w};
        }
    }
    #pragma unroll
    for (int ks = 0; ks < 8; ++ks) {
        const int kb = ks * 32 + lhi * 8;
        bf16x8 bH[4];
        #pragma unroll
        for (int nt = 0; nt < 4; ++nt)
            bH[nt] = *(const bf16x8*)&xs[swz64(nt * 16 + llo, kb)];
        __builtin_amdgcn_s_setprio(1);
        #pragma unroll
        for (int nt = 0; nt < 4; ++nt) {
            acc2[nt][0] = __builtin_amdgcn_mfma_f32_16x16x32_bf16(
                aW2[ks & 1][0], bH[nt], acc2[nt][0], 0, 0, 0);
            acc2[nt][1] = __builtin_amdgcn_mfma_f32_16x16x32_bf16(
                aW2[ks & 1][1], bH[nt], acc2[nt][1], 0, 0, 0);
        }
        __builtin_amdgcn_s_setprio(0);
        if (ks < 6) {
            aW2[ks & 1][0] = *(const bf16x8*)(w2pA + (ks + 2) * 32);
            aW2[ks & 1][1] = *(const bf16x8*)(w2pB + (ks + 2) * 32);
        }
    }

    // ---- store out: full 128B lines per wave, non-temporal float4 ----
    #pragma unroll
    for (int nt = 0; nt < 4; ++nt) {
        const int node = base + nt * 16 + llo;
        if (node < N) {
            float* op = out + (size_t)node * 128 + wave * 32 + lhi * 4;
            __builtin_nontemporal_store(acc2[nt][0], (f32x4*)op);
            __builtin_nontemporal_store(acc2[nt][1], (f32x4*)(op + 16));
        }
    }
}

// ---------------------------------------------------------------------------
extern "C" void kernel_launch(void* const* d_in, const int* in_sizes, int n_in,
                              void* d_out, int out_size, void* d_ws, size_t ws_size,
                              hipStream_t stream)
{
    const float* h_topo = (const float*)d_in[0];
    const float* h_geom = (const float*)d_in[1];
    const int*   batch  = (const int*)  d_in[2];
    const float* W1     = (const float*)d_in[3];
    const float* b1     = (const float*)d_in[4];
    const float* W2     = (const float*)d_in[5];
    const float* b2     = (const float*)d_in[6];
    float* out = (float*)d_out;

    const int N = in_sizes[0] / D;   // 200000

    // ws layout: pp (8MB) | P (512KB) | W1bT | W2bT | seg (~2KB)
    float*          pp   = (float*)d_ws;
    float*          P    = pp + (size_t)NUM_GRAPHS * 2 * NS * 256;
    unsigned short* W1bT = (unsigned short*)(P + (size_t)NUM_GRAPHS * 256);
    unsigned short* W2bT = W1bT + 256 * 256;
    int*            seg  = (int*)(W2bT + 128 * 256);

    bounds_kernel<<<3, 256, 0, stream>>>(batch, N, seg);
    wconv_kernel<<<(256 * 256 + 128 * 256) / 256, 256, 0, stream>>>(W1, W2, W1bT, W2bT);
    pool_kernel<<<dim3(NUM_GRAPHS, 2, NS), 256, 0, stream>>>(h_topo, h_geom, seg, N, pp);
    pmat_kernel<<<NUM_GRAPHS, 256, 0, stream>>>(pp, seg, W1, b1, P);

    const int nblocks = (N + BN - 1) / BN;   // 3125
    mlp_mfma<<<nblocks, 256, 0, stream>>>(h_topo, h_geom, batch, P,
                                          W1bT, W2bT, b2, out, N);
}

// Round 16
// 170.336 us; speedup vs baseline: 1.1389x; 1.0979x over previous
//
#include <hip/hip_runtime.h>
#include <math.h>

#define NUM_GRAPHS 512
#define D 128
#define NEG 0.01f
#define BN 128  // nodes per block in MFMA MLP kernel
#define NS 8    // pool row-slices per (graph, tensor)

typedef __attribute__((ext_vector_type(8))) short  bf16x8;  // MFMA A/B frag
typedef __attribute__((ext_vector_type(4))) float  f32x4;   // MFMA C/D frag
typedef __attribute__((ext_vector_type(4))) int    i32x4;

__device__ __forceinline__ unsigned short f2bf(float f) {
    unsigned u = __float_as_uint(f);
    u += 0x7fffu + ((u >> 16) & 1u);   // RNE
    return (unsigned short)(u >> 16);
}

// f32x8 -> 16B of bf16 via packed cvt
__device__ __forceinline__ bf16x8 cvt8(float4 a, float4 b) {
    unsigned w0, w1, w2, w3;
    asm("v_cvt_pk_bf16_f32 %0, %1, %2" : "=v"(w0) : "v"(a.x), "v"(a.y));
    asm("v_cvt_pk_bf16_f32 %0, %1, %2" : "=v"(w1) : "v"(a.z), "v"(a.w));
    asm("v_cvt_pk_bf16_f32 %0, %1, %2" : "=v"(w2) : "v"(b.x), "v"(b.y));
    asm("v_cvt_pk_bf16_f32 %0, %1, %2" : "=v"(w3) : "v"(b.z), "v"(b.w));
    i32x4 v; v[0] = (int)w0; v[1] = (int)w1; v[2] = (int)w2; v[3] = (int)w3;
    return __builtin_bit_cast(bf16x8, v);
}

// swizzled ushort index in the 128-row two-tile LDS image
__device__ __forceinline__ int swz128(int row, int k) {
    return (row >> 6) * 16384 + (row & 63) * 256 + (k ^ ((row & 7) << 3));
}

// raw barrier that does NOT drain vmcnt (keeps global prefetch in flight);
// lgkmcnt(0) publishes LDS writes / retires LDS reads.
#define LDS_BARRIER()                                                        \
    do {                                                                     \
        asm volatile("s_waitcnt lgkmcnt(0)" ::: "memory");                   \
        __builtin_amdgcn_s_barrier();                                        \
        asm volatile("" ::: "memory");                                       \
    } while (0)

#define FMAX4(a, b)                                                          \
    do {                                                                     \
        (a).x = fmaxf((a).x, (b).x); (a).y = fmaxf((a).y, (b).y);            \
        (a).z = fmaxf((a).z, (b).z); (a).w = fmaxf((a).w, (b).w);            \
    } while (0)
#define FADD4(a, b)                                                          \
    do {                                                                     \
        (a).x += (b).x; (a).y += (b).y; (a).z += (b).z; (a).w += (b).w;      \
    } while (0)

// ---------------------------------------------------------------------------
// Kernel 0: segment bounds. seg[g] = lower_bound(batch, g), g in [0, 512].
// ---------------------------------------------------------------------------
__global__ __launch_bounds__(256) void bounds_kernel(
    const int* __restrict__ batch, int N, int* __restrict__ seg)
{
    const int g = blockIdx.x * 256 + threadIdx.x;
    if (g <= NUM_GRAPHS) {
        int lo = 0, hi = N;
        while (lo < hi) { int m = (lo + hi) >> 1; if (batch[m] < g) lo = m + 1; else hi = m; }
        seg[g] = lo;
    }
}

// ---------------------------------------------------------------------------
// Kernel 1: sliced per-graph segment max+sum partials (pure reduction).
// grid=(512, 2, NS); 4 independent acc streams for MLP.
// pp[((g*2+t)*NS+s)*256 + {0..127: max, 128..255: sum}]
// ---------------------------------------------------------------------------
__global__ __launch_bounds__(256) void pool_kernel(
    const float* __restrict__ h_topo, const float* __restrict__ h_geom,
    const int* __restrict__ seg, int N, float* __restrict__ pp)
{
    const int g = blockIdx.x, t = blockIdx.y, s = blockIdx.z;
    const float* __restrict__ h = t ? h_geom : h_topo;

    const int start = seg[g], end = seg[g + 1];
    const int len = end - start;
    const int r0  = start + (int)(((long long)len * s) / NS);
    const int r1  = start + (int)(((long long)len * (s + 1)) / NS);

    const int c = threadIdx.x & 31;   // float4 column
    const int r = threadIdx.x >> 5;   // 0..7 row phase

    float4 mxA = make_float4(-INFINITY, -INFINITY, -INFINITY, -INFINITY);
    float4 mxB = mxA, mxC = mxA, mxD = mxA;
    float4 smA = make_float4(0.f, 0.f, 0.f, 0.f);
    float4 smB = smA, smC = smA, smD = smA;

    int row = r0 + r;
    for (; row + 24 < r1; row += 32) {
        float4 v0 = *(const float4*)(h + (size_t)row * D + c * 4);
        float4 v1 = *(const float4*)(h + (size_t)(row + 8)  * D + c * 4);
        float4 v2 = *(const float4*)(h + (size_t)(row + 16) * D + c * 4);
        float4 v3 = *(const float4*)(h + (size_t)(row + 24) * D + c * 4);
        FMAX4(mxA, v0); FADD4(smA, v0);
        FMAX4(mxB, v1); FADD4(smB, v1);
        FMAX4(mxC, v2); FADD4(smC, v2);
        FMAX4(mxD, v3); FADD4(smD, v3);
    }
    for (; row < r1; row += 8) {
        float4 v = *(const float4*)(h + (size_t)row * D + c * 4);
        FMAX4(mxA, v); FADD4(smA, v);
    }
    FMAX4(mxA, mxB); FMAX4(mxC, mxD); FMAX4(mxA, mxC);
    FADD4(smA, smB); FADD4(smC, smD); FADD4(smA, smC);

    __shared__ float4 smx[256], ssm[256];
    smx[threadIdx.x] = mxA; ssm[threadIdx.x] = smA;
    __syncthreads();
    #pragma unroll
    for (int st = 4; st > 0; st >>= 1) {
        if (r < st) {
            float4 a = smx[threadIdx.x + st * 32];
            float4 b = ssm[threadIdx.x + st * 32];
            float4 m0 = smx[threadIdx.x];
            float4 s0 = ssm[threadIdx.x];
            FMAX4(m0, a); FADD4(s0, b);
            smx[threadIdx.x] = m0; ssm[threadIdx.x] = s0;
        }
        __syncthreads();
    }
    if (r == 0) {
        float* dst = pp + ((size_t)(g * 2 + t) * NS + s) * 256;
        *(float4*)(dst + c * 4)       = smx[threadIdx.x];   // raw max partial
        *(float4*)(dst + 128 + c * 4) = ssm[threadIdx.x];   // raw sum partial
    }
}

// ---------------------------------------------------------------------------
// Kernel 2: finalize partials + per-graph bias
// P[g][j] = b1[j] + pooled[g] . W1[pooled rows][j]
// ---------------------------------------------------------------------------
__global__ __launch_bounds__(256) void pmat_kernel(
    const float* __restrict__ pp, const int* __restrict__ seg,
    const float* __restrict__ W1, const float* __restrict__ b1,
    float* __restrict__ P)
{
    const int g = blockIdx.x;
    const int j = threadIdx.x;

    const int start = seg[g], end = seg[g + 1];
    const float inv   = 1.0f / fmaxf((float)(end - start), 1.0f);
    const bool  empty = (end <= start);

    __shared__ float pl[512];
    #pragma unroll
    for (int e0 = 0; e0 < 2; ++e0) {
        const int e = j + e0 * 256;
        const int t = e >> 8, i = e & 255;
        const float* q = pp + (size_t)(g * 2 + t) * NS * 256 + i;
        float v;
        if (i < 128) {
            v = q[0];
            #pragma unroll
            for (int s = 1; s < NS; ++s) v = fmaxf(v, q[s * 256]);
        } else {
            v = q[0];
            #pragma unroll
            for (int s = 1; s < NS; ++s) v += q[s * 256];
            v *= inv;
        }
        pl[e] = empty ? 0.f : v;
    }
    __syncthreads();

    float acc = b1[j];
    #pragma unroll 8
    for (int k = 0; k < 256; ++k)          // t_max,t_mean -> W1 rows 128..383
        acc += pl[k] * W1[(size_t)(128 + k) * 256 + j];
    #pragma unroll 8
    for (int k = 0; k < 256; ++k)          // g_max,g_mean -> W1 rows 512..767
        acc += pl[256 + k] * W1[(size_t)(512 + k) * 256 + j];

    P[(size_t)g * 256 + j] = acc;
}

// ---------------------------------------------------------------------------
// Kernel 3: weight pre-convert to transposed bf16.
// ---------------------------------------------------------------------------
__global__ __launch_bounds__(256) void wconv_kernel(
    const float* __restrict__ W1, const float* __restrict__ W2,
    unsigned short* __restrict__ W1bT, unsigned short* __restrict__ W2bT)
{
    const int idx = blockIdx.x * 256 + threadIdx.x;
    if (idx < 256 * 256) {
        const int n = idx >> 8, k = idx & 255;
        const int kk = (k < 128) ? k : (k + 256);
        W1bT[idx] = f2bf(W1[(size_t)kk * 256 + n]);
    } else {
        const int j = idx - 256 * 256;
        if (j < 128 * 256) {
            const int n = j >> 8, k = j & 255;
            W2bT[j] = f2bf(W2[(size_t)k * 128 + n]);
        }
    }
}

// ---------------------------------------------------------------------------
// Kernel 4: fused MFMA MLP (R12 configuration — best measured: mlp ~120us).
// 128 nodes/block, 8 waves. X staged by reading h_topo/h_geom f32 directly,
// converted in-register. GEMM2 transposed (A=W2 frag, B=H frag) so D=[j][node]
// and each lane stores a contiguous float4 of out, non-temporal.
// ---------------------------------------------------------------------------
__global__ __launch_bounds__(512, 4) void mlp_mfma(
    const float* __restrict__ h_topo, const float* __restrict__ h_geom,
    const int* __restrict__ batch, const float* __restrict__ P,
    const unsigned short* __restrict__ W1bT, const unsigned short* __restrict__ W2bT,
    const float* __restrict__ b2, float* __restrict__ out, int N)
{
    __shared__ unsigned short xs[128 * 256];   // 64 KB, X then H (swz128 layout)
    __shared__ int gid[128];

    const int tid  = threadIdx.x;
    const int wave = tid >> 6, lane = tid & 63;
    const int base = blockIdx.x * BN;

    // ---- stage X: row = tid>>2 (0..127), kq = tid&3 (64-dim chunk) ----
    {
        const int row  = tid >> 2, kq = tid & 3;
        const int node = min(base + row, N - 1);
        const float* src = (kq < 2) ? h_topo + (size_t)node * D + kq * 64
                                    : h_geom + (size_t)node * D + (kq - 2) * 64;
        #pragma unroll
        for (int i = 0; i < 8; ++i) {
            float4 a = ((const float4*)src)[2 * i];
            float4 b = ((const float4*)src)[2 * i + 1];
            *(bf16x8*)&xs[swz128(row, kq * 64 + i * 8)] = cvt8(a, b);
        }
    }
    if (tid < 128) gid[tid] = batch[min(base + tid, N - 1)];

    const int g0 = batch[base];
    const int g1 = batch[min(base + 127, N - 1)];
    const bool uni = (g0 == g1);

    const int lhi = lane >> 4;   // 0..3
    const int llo = lane & 15;   // 0..15

    const unsigned short* w1p = W1bT + (size_t)(wave * 32 + llo) * 256 + lhi * 8;
    const unsigned short* w2p = W2bT + (size_t)(wave * 16 + llo) * 256 + lhi * 8;

    float pf[2];
    if (uni) {
        #pragma unroll
        for (int ct = 0; ct < 2; ++ct)
            pf[ct] = P[(size_t)g0 * 256 + wave * 32 + ct * 16 + llo];
    }

    // ---- preload GEMM1 ks=0,1 weight frags (stay pending across barrier) ----
    bf16x8 bfr[2][2];
    #pragma unroll
    for (int ct = 0; ct < 2; ++ct) {
        bfr[0][ct] = *(const bf16x8*)(w1p + (size_t)ct * 16 * 256);
        bfr[1][ct] = *(const bf16x8*)(w1p + (size_t)ct * 16 * 256 + 32);
    }

    LDS_BARRIER();   // X image published (lgkm only; weight vm loads in flight)

    // ---- GEMM1: 8 row-tiles x 2 col-tiles, dist-2 W prefetch ----
    f32x4 acc[8][2];
    #pragma unroll
    for (int rt = 0; rt < 8; ++rt)
        #pragma unroll
        for (int ct = 0; ct < 2; ++ct) {
            const float p = uni ? pf[ct] : 0.f;
            acc[rt][ct] = (f32x4){p, p, p, p};
        }

    #pragma unroll
    for (int ks = 0; ks < 8; ++ks) {
        const int kb = ks * 32 + lhi * 8;
        bf16x8 afr[8];
        #pragma unroll
        for (int rt = 0; rt < 8; ++rt)
            afr[rt] = *(const bf16x8*)&xs[swz128(rt * 16 + llo, kb)];
        __builtin_amdgcn_s_setprio(1);
        #pragma unroll
        for (int rt = 0; rt < 8; ++rt)
            #pragma unroll
            for (int ct = 0; ct < 2; ++ct)
                acc[rt][ct] = __builtin_amdgcn_mfma_f32_16x16x32_bf16(
                    afr[rt], bfr[ks & 1][ct], acc[rt][ct], 0, 0, 0);
        __builtin_amdgcn_s_setprio(0);
        if (ks < 6) {
            const int kbn = (ks + 2) * 32;
            #pragma unroll
            for (int ct = 0; ct < 2; ++ct)
                bfr[ks & 1][ct] = *(const bf16x8*)(w1p + (size_t)ct * 16 * 256 + kbn);
        }
    }

    // ---- issue GEMM2 ks=0,1 W2 frags (in flight across barriers) ----
    bf16x8 bfr2[2];
    bfr2[0] = *(const bf16x8*)(w2p);
    bfr2[1] = *(const bf16x8*)(w2p + 32);

    LDS_BARRIER();   // all waves done reading X (lgkm only)

    // ---- epilogue 1: (+P if boundary tile), LeakyReLU, H -> xs (bf16) ----
    #pragma unroll
    for (int rt = 0; rt < 8; ++rt) {
        #pragma unroll
        for (int ct = 0; ct < 2; ++ct) {
            const int col = wave * 32 + ct * 16 + llo;
            #pragma unroll
            for (int q = 0; q < 4; ++q) {
                const int row = rt * 16 + lhi * 4 + q;
                float v = acc[rt][ct][q];
                if (!uni) v += P[(size_t)gid[row] * 256 + col];
                v = fmaxf(v, NEG * v);   // LeakyReLU
                xs[swz128(row, col)] = f2bf(v);
            }
        }
    }

    LDS_BARRIER();   // H published

    // ---- GEMM2 (transposed): D[j][node] = W2T . H^T ----
    f32x4 acc2[8];
    {
        const float4 bb = *(const float4*)(b2 + wave * 16 + lhi * 4);
        #pragma unroll
        for (int rt = 0; rt < 8; ++rt)
            acc2[rt] = (f32x4){bb.x, bb.y, bb.z, bb.w};
    }
    #pragma unroll
    for (int ks = 0; ks < 8; ++ks) {
        const int kb = ks * 32 + lhi * 8;
        bf16x8 hfr[8];
        #pragma unroll
        for (int rt = 0; rt < 8; ++rt)
            hfr[rt] = *(const bf16x8*)&xs[swz128(rt * 16 + llo, kb)];
        __builtin_amdgcn_s_setprio(1);
        #pragma unroll
        for (int rt = 0; rt < 8; ++rt)
            acc2[rt] = __builtin_amdgcn_mfma_f32_16x16x32_bf16(
                bfr2[ks & 1], hfr[rt], acc2[rt], 0, 0, 0);
        __builtin_amdgcn_s_setprio(0);
        if (ks < 6)
            bfr2[ks & 1] = *(const bf16x8*)(w2p + (ks + 2) * 32);
    }

    // ---- store out: per-lane float4, non-temporal ----
    #pragma unroll
    for (int rt = 0; rt < 8; ++rt) {
        const int node = base + rt * 16 + llo;
        if (node < N)
            __builtin_nontemporal_store(
                acc2[rt],
                (f32x4*)(out + (size_t)node * 128 + wave * 16 + lhi * 4));
    }
}

// ---------------------------------------------------------------------------
extern "C" void kernel_launch(void* const* d_in, const int* in_sizes, int n_in,
                              void* d_out, int out_size, void* d_ws, size_t ws_size,
                              hipStream_t stream)
{
    const float* h_topo = (const float*)d_in[0];
    const float* h_geom = (const float*)d_in[1];
    const int*   batch  = (const int*)  d_in[2];
    const float* W1     = (const float*)d_in[3];
    const float* b1     = (const float*)d_in[4];
    const float* W2     = (const float*)d_in[5];
    const float* b2     = (const float*)d_in[6];
    float* out = (float*)d_out;

    const int N = in_sizes[0] / D;   // 200000

    // ws layout: pp (8MB) | P (512KB) | W1bT | W2bT | seg (~2KB)
    float*          pp   = (float*)d_ws;
    float*          P    = pp + (size_t)NUM_GRAPHS * 2 * NS * 256;
    unsigned short* W1bT = (unsigned short*)(P + (size_t)NUM_GRAPHS * 256);
    unsigned short* W2bT = W1bT + 256 * 256;
    int*            seg  = (int*)(W2bT + 128 * 256);

    bounds_kernel<<<3, 256, 0, stream>>>(batch, N, seg);
    wconv_kernel<<<(256 * 256 + 128 * 256) / 256, 256, 0, stream>>>(W1, W2, W1bT, W2bT);
    pool_kernel<<<dim3(NUM_GRAPHS, 2, NS), 256, 0, stream>>>(h_topo, h_geom, seg, N, pp);
    pmat_kernel<<<NUM_GRAPHS, 256, 0, stream>>>(pp, seg, W1, b1, P);

    const int nblocks = (N + BN - 1) / BN;   // 1563
    mlp_mfma<<<nblocks, 512, 0, stream>>>(h_topo, h_geom, batch, P,
                                          W1bT, W2bT, b2, out, N);
}